// Round 1
// 664.111 us; speedup vs baseline: 1.1527x; 1.1527x over previous
//
#include <hip/hip_runtime.h>
#include <hip/hip_bf16.h>
#include <stdint.h>

#define N_NODES 100000
#define DIM 256
#define HID 512
#define N_EDGES 1600000

// two-level bucket sort params: 782 buckets of 128 dst nodes each
#define NBUCK 782                  // 782*128 = 100096 >= N_NODES
#define BSHIFT 7
#define BMASK 127
#define CAPC 4096                  // per-bucket capacity (mean 2048, sigma ~45 -> +45 sigma)
#define CURSTRIDE 16               // one cursor per 64B line

using short8 = __attribute__((ext_vector_type(8))) short;
using f32x4  = __attribute__((ext_vector_type(4))) float;

__device__ __forceinline__ unsigned short f2bf(float f) {
    union { float f; unsigned u; } v; v.f = f;
    unsigned u = v.u;
    unsigned r = u + 0x7fffu + ((u >> 16) & 1u);   // RNE
    return (unsigned short)(r >> 16);
}
__device__ __forceinline__ float bf2f(unsigned short u) {
    union { unsigned u; float f; } v; v.u = ((unsigned)u) << 16; return v.f;
}
__device__ __forceinline__ void gload_lds16(const void* g, void* l) {
    __builtin_amdgcn_global_load_lds((const __attribute__((address_space(1))) void*)g,
                                     (__attribute__((address_space(3))) void*)l, 16, 0, 0);
}

// x fp32 -> bf16, 8 elems/thread
__global__ void x2bf(const float* __restrict__ x, unsigned short* __restrict__ xb) {
    long i = (long)blockIdx.x * blockDim.x + threadIdx.x;
    float4 u0 = ((const float4*)x)[i * 2];
    float4 u1 = ((const float4*)x)[i * 2 + 1];
    short8 o;
    o[0] = (short)f2bf(u0.x); o[1] = (short)f2bf(u0.y);
    o[2] = (short)f2bf(u0.z); o[3] = (short)f2bf(u0.w);
    o[4] = (short)f2bf(u1.x); o[5] = (short)f2bf(u1.y);
    o[6] = (short)f2bf(u1.z); o[7] = (short)f2bf(u1.w);
    ((short8*)xb)[i] = o;
}

// ---------------- two-level bucket sort (CSR by dst) ----------------

__global__ void zero_cursors(int* __restrict__ chunkCursor) {
    int i = blockIdx.x * 256 + threadIdx.x;
    if (i < NBUCK * CURSTRIDE) chunkCursor[i] = 0;
}

// pass 1: scatter edges into fixed-stride buckets of 128 dst nodes.
// packed word: src (17 bits) | (dst & 127) << 17
__global__ void bucket_scatter(const int* __restrict__ src, const int* __restrict__ dst,
                               int* __restrict__ chunkCursor, int* __restrict__ bucketed) {
    int e = blockIdx.x * 256 + threadIdx.x;
    int d = dst[e];
    int c = d >> BSHIFT;
    int pos = atomicAdd(&chunkCursor[c * CURSTRIDE], 1);
    bucketed[(size_t)c * CAPC + pos] = src[e] | ((d & BMASK) << 17);
}

// exclusive scan of bucket counts (cursors after pass 1 ARE the counts)
__global__ void scan_chunks(const int* __restrict__ chunkCursor, int* __restrict__ chunkOff) {
    __shared__ int sm[1024];
    int t = threadIdx.x;
    int v = (t < NBUCK) ? chunkCursor[t * CURSTRIDE] : 0;
    sm[t] = v;
    __syncthreads();
    for (int off = 1; off < 1024; off <<= 1) {
        int add = (t >= off) ? sm[t - off] : 0;
        __syncthreads();
        sm[t] += add;
        __syncthreads();
    }
    chunkOff[t] = sm[t] - v;   // exclusive
}

// pass 2: per-bucket counting sort in LDS; emits sorted_src, start[], count[]
__global__ __launch_bounds__(256) void chunk_sort(const int* __restrict__ bucketed,
        const int* __restrict__ chunkCursor, const int* __restrict__ chunkOff,
        int* __restrict__ start, int* __restrict__ count, int* __restrict__ sorted_src) {
    __shared__ int cnt[128];
    __shared__ int cur[128];
    __shared__ int sortedL[CAPC];
    int c = blockIdx.x;
    int t = threadIdx.x;
    int nE = chunkCursor[c * CURSTRIDE];
    int base = chunkOff[c];
    const int* bk = bucketed + (size_t)c * CAPC;
    if (t < 128) cnt[t] = 0;
    __syncthreads();
    for (int i = t; i < nE; i += 256)
        atomicAdd(&cnt[bk[i] >> 17], 1);
    __syncthreads();
    int v = (t < 128) ? cnt[t] : 0;
    // Hillis-Steele inclusive scan over 128 bins
    for (int off = 1; off < 128; off <<= 1) {
        int add = (t >= off && t < 128) ? cnt[t - off] : 0;
        __syncthreads();
        if (t < 128) cnt[t] += add;
        __syncthreads();
    }
    if (t < 128) {
        int excl = cnt[t] - v;
        int gid = c * 128 + t;
        start[gid] = base + excl;
        count[gid] = v;
        cur[t] = excl;
    }
    __syncthreads();
    for (int i = t; i < nE; i += 256) {
        int p = bk[i];
        int pos = atomicAdd(&cur[p >> 17], 1);
        sortedL[pos] = p & 0x1FFFF;
    }
    __syncthreads();
    for (int i = t; i < nE; i += 256)
        sorted_src[base + i] = sortedL[i];
}

// one wave per node, bf16 rows: accb[n] = bf16( (1+eps)*x[n] + sum_neigh x[s] )
__global__ void gather_sum(const unsigned short* __restrict__ xb, const int* __restrict__ sorted_src,
                           const int* __restrict__ start, const int* __restrict__ count,
                           const float* __restrict__ eps, unsigned short* __restrict__ accb) {
    int lane = threadIdx.x & 63;
    int n = blockIdx.x * 4 + (threadIdx.x >> 6);
    if (n >= N_NODES) return;
    float s = 1.0f + eps[0];
    const ushort4* xr = (const ushort4*)(xb + (size_t)n * DIM);
    ushort4 v = xr[lane];
    float a0 = bf2f(v.x) * s, a1 = bf2f(v.y) * s, a2 = bf2f(v.z) * s, a3 = bf2f(v.w) * s;
    int base = start[n];
    int end = base + count[n];
    int j = base;
    for (; j + 4 <= end; j += 4) {
        int s0 = sorted_src[j], s1 = sorted_src[j + 1];
        int s2 = sorted_src[j + 2], s3 = sorted_src[j + 3];
        ushort4 v0 = ((const ushort4*)(xb + (size_t)s0 * DIM))[lane];
        ushort4 v1 = ((const ushort4*)(xb + (size_t)s1 * DIM))[lane];
        ushort4 v2 = ((const ushort4*)(xb + (size_t)s2 * DIM))[lane];
        ushort4 v3 = ((const ushort4*)(xb + (size_t)s3 * DIM))[lane];
        a0 += bf2f(v0.x) + bf2f(v1.x) + bf2f(v2.x) + bf2f(v3.x);
        a1 += bf2f(v0.y) + bf2f(v1.y) + bf2f(v2.y) + bf2f(v3.y);
        a2 += bf2f(v0.z) + bf2f(v1.z) + bf2f(v2.z) + bf2f(v3.z);
        a3 += bf2f(v0.w) + bf2f(v1.w) + bf2f(v2.w) + bf2f(v3.w);
    }
    for (; j < end; ++j) {
        int s0 = sorted_src[j];
        ushort4 v0 = ((const ushort4*)(xb + (size_t)s0 * DIM))[lane];
        a0 += bf2f(v0.x); a1 += bf2f(v0.y); a2 += bf2f(v0.z); a3 += bf2f(v0.w);
    }
    ushort4 o;
    o.x = f2bf(a0); o.y = f2bf(a1); o.z = f2bf(a2); o.w = f2bf(a3);
    ((ushort4*)(accb + (size_t)n * DIM))[lane] = o;
}

// ---------------- MLP ----------------

__global__ void prep_weights(const float* __restrict__ W1, const float* __restrict__ W2,
                             unsigned short* __restrict__ W1t, unsigned short* __restrict__ W2t) {
    int tid = blockIdx.x * blockDim.x + threadIdx.x;
    if (tid < DIM * HID) {
        int n = tid >> 8, k = tid & 255;
        W1t[tid] = f2bf(W1[k * HID + n]);
    } else {
        int j = tid - DIM * HID;
        int n = j >> 9, k = j & 511;
        W2t[j] = f2bf(W2[k * DIM + n]);
    }
}

// 128x128 tile, 4 waves (2x2), each 64x64 via 4x4 of 16x16x32 bf16 MFMA.
// global_load_lds(16B) staging; LDS chunk XOR-swizzle keeps ds_read_b128 at 2-way.
// A row-major bf16 [M][K]; Bt n-major bf16 [NOUT][K].
template<int K, int NOUT, bool RELU_BF16_OUT>
__global__ __launch_bounds__(256) void gemm128(const unsigned short* __restrict__ A,
        const unsigned short* __restrict__ Bt, const float* __restrict__ bias,
        void* __restrict__ Cout, int M) {
    __shared__ unsigned short As[128 * 32];   // 8 KB, row stride 64 B, no pad
    __shared__ unsigned short Bs[128 * 32];
    constexpr int NT = NOUT / 128;
    int mtile = blockIdx.x / NT;
    int ntile = blockIdx.x % NT;
    int mbase = mtile * 128, nbase = ntile * 128;
    int t = threadIdx.x;
    int lane = t & 63, wid = t >> 6;
    int wm = (wid & 1) * 64, wn = (wid >> 1) * 64;
    int lo = lane & 15, quad = lane >> 4;

    // staging slot -> (row, stored-chunk, global-chunk)
    int s0 = t, s1 = t + 256;
    int r0 = s0 >> 2, c0 = (s0 & 3) ^ ((r0 >> 1) & 3);
    int r1 = s1 >> 2, c1 = (s1 & 3) ^ ((r1 >> 1) & 3);
    int gmA0 = mbase + r0; if (gmA0 >= M) gmA0 = M - 1;
    int gmA1 = mbase + r1; if (gmA1 >= M) gmA1 = M - 1;
    const unsigned short* gA0 = A + (size_t)gmA0 * K + c0 * 8;
    const unsigned short* gA1 = A + (size_t)gmA1 * K + c1 * 8;
    const unsigned short* gB0 = Bt + (size_t)(nbase + r0) * K + c0 * 8;
    const unsigned short* gB1 = Bt + (size_t)(nbase + r1) * K + c1 * 8;
    char* lA0 = (char*)As + wid * 1024;
    char* lA1 = (char*)As + 4096 + wid * 1024;
    char* lB0 = (char*)Bs + wid * 1024;
    char* lB1 = (char*)Bs + 4096 + wid * 1024;

    // fragment LDS byte offsets (XOR-swizzled chunk)
    int offA[4], offB[4];
    #pragma unroll
    for (int i = 0; i < 4; ++i) {
        int ra = wm + i * 16 + lo;
        offA[i] = ra * 64 + ((quad ^ ((ra >> 1) & 3)) * 16);
        int rb = wn + i * 16 + lo;
        offB[i] = rb * 64 + ((quad ^ ((rb >> 1) & 3)) * 16);
    }

    f32x4 acc[4][4] = {};
    for (int kt = 0; kt < K / 32; ++kt) {
        if (kt) __syncthreads();
        int ko = kt * 32;
        gload_lds16(gA0 + ko, lA0);
        gload_lds16(gA1 + ko, lA1);
        gload_lds16(gB0 + ko, lB0);
        gload_lds16(gB1 + ko, lB1);
        __syncthreads();
        short8 a[4], b[4];
        #pragma unroll
        for (int i = 0; i < 4; ++i) {
            a[i] = *(const short8*)((const char*)As + offA[i]);
            b[i] = *(const short8*)((const char*)Bs + offB[i]);
        }
        #pragma unroll
        for (int mi = 0; mi < 4; ++mi)
            #pragma unroll
            for (int ni = 0; ni < 4; ++ni)
                acc[mi][ni] = __builtin_amdgcn_mfma_f32_16x16x32_bf16(a[mi], b[ni], acc[mi][ni], 0, 0, 0);
    }
    // epilogue: D layout col=lane&15, row=quad*4+reg
    #pragma unroll
    for (int mi = 0; mi < 4; ++mi)
      #pragma unroll
      for (int ni = 0; ni < 4; ++ni)
        #pragma unroll
        for (int r = 0; r < 4; ++r) {
            int row = mbase + wm + mi * 16 + quad * 4 + r;
            int col = nbase + wn + ni * 16 + lo;
            if (row < M) {
                float v = acc[mi][ni][r] + bias[col];
                if constexpr (RELU_BF16_OUT) {
                    v = fmaxf(v, 0.0f);
                    ((unsigned short*)Cout)[(size_t)row * NOUT + col] = f2bf(v);
                } else {
                    ((float*)Cout)[(size_t)row * NOUT + col] = v;
                }
            }
        }
}

// ---------------- BatchNorm ----------------

__global__ void col_stats1(const float* __restrict__ h, float* __restrict__ partial) {
    int t = threadIdx.x;
    int b = blockIdx.x;
    int r0 = b * 200;
    int r1 = r0 + 200; if (r1 > N_NODES) r1 = N_NODES;
    float s = 0.f, q = 0.f;
    for (int r = r0; r < r1; ++r) {
        float v = h[(size_t)r * DIM + t];
        s += v; q += v * v;
    }
    partial[b * 512 + t] = s;
    partial[b * 512 + 256 + t] = q;
}

__global__ void col_stats2(const float* __restrict__ partial, const float* __restrict__ gamma,
                           const float* __restrict__ beta, float* __restrict__ sc) {
    int t = threadIdx.x;
    float s = 0.f, q = 0.f;
    for (int b = 0; b < 500; ++b) {
        s += partial[b * 512 + t];
        q += partial[b * 512 + 256 + t];
    }
    float mean = s * (1.0f / (float)N_NODES);
    float var = q * (1.0f / (float)N_NODES) - mean * mean;
    float inv = rsqrtf(var + 1e-5f);
    float scale = gamma[t] * inv;
    sc[t] = scale;
    sc[256 + t] = beta[t] - mean * scale;
}

__global__ void bn_apply(const float* __restrict__ h, const float* __restrict__ sc,
                         float* __restrict__ out) {
    long i = (long)blockIdx.x * blockDim.x + threadIdx.x;
    int c = (int)((i * 4) & (DIM - 1));
    float4 v = ((const float4*)h)[i];
    float4 scale = *(const float4*)(sc + c);
    float4 shift = *(const float4*)(sc + 256 + c);
    float4 o;
    o.x = v.x * scale.x + shift.x;
    o.y = v.y * scale.y + shift.y;
    o.z = v.z * scale.z + shift.z;
    o.w = v.w * scale.w + shift.w;
    ((float4*)out)[i] = o;
}

extern "C" void kernel_launch(void* const* d_in, const int* in_sizes, int n_in,
                              void* d_out, int out_size, void* d_ws, size_t ws_size,
                              hipStream_t stream) {
    const float* x     = (const float*)d_in[0];
    const int*   src   = (const int*)d_in[1];
    const int*   dst   = (const int*)d_in[2];
    const float* eps   = (const float*)d_in[3];
    const float* W1    = (const float*)d_in[4];
    const float* b1    = (const float*)d_in[5];
    const float* W2    = (const float*)d_in[6];
    const float* b2    = (const float*)d_in[7];
    const float* gamma = (const float*)d_in[8];
    const float* beta  = (const float*)d_in[9];

    char* ws = (char*)d_ws;
    unsigned short* xb   = (unsigned short*)ws;                   // 51,200,000 B (dead after gather)
    unsigned short* accb = (unsigned short*)(ws + 51200000);      // 51,200,000 B (dead after GEMM1)
    float*          h2   = (float*)ws;                            // 102,400,000 B (overlaps xb+accb, written by GEMM2)
    unsigned short* W1t  = (unsigned short*)(ws + 102400000);     // 262,144 B
    unsigned short* W2t  = (unsigned short*)(ws + 102662144);     // 262,144 B
    float*          sc   = (float*)(ws + 102924288);              // 2,048 B

    // d_out phases: [sort scratch] -> [tbuf bf16 N x 512] -> [partial] -> [final out]
    char* ob = (char*)d_out;
    int* chunkCursor = (int*)ob;                   // 782*16*4 = 50,048 B (padded to 51,200)
    int* chunkOff    = (int*)(ob + 51200);         // 4,096 B
    int* start       = (int*)(ob + 55296);         // 400,384 B
    int* count       = (int*)(ob + 455680);        // 400,384 B
    int* sorted_src  = (int*)(ob + 856064);        // 6,400,000 B
    int* bucketed    = (int*)(ob + 7256064);       // 782*4096*4 = 12,812,288 B (ends at 20,068,352)
    unsigned short* tbuf    = (unsigned short*)d_out;
    float*          partial = (float*)d_out;       // 1,024,000 B, after GEMM2
    float*          out     = (float*)d_out;

    hipLaunchKernelGGL(x2bf, dim3(12500), dim3(256), 0, stream, x, xb);
    hipLaunchKernelGGL(prep_weights, dim3(1024), dim3(256), 0, stream, W1, W2, W1t, W2t);
    hipLaunchKernelGGL(zero_cursors, dim3(49), dim3(256), 0, stream, chunkCursor);
    hipLaunchKernelGGL(bucket_scatter, dim3(N_EDGES / 256), dim3(256), 0, stream,
                       src, dst, chunkCursor, bucketed);
    hipLaunchKernelGGL(scan_chunks, dim3(1), dim3(1024), 0, stream, chunkCursor, chunkOff);
    hipLaunchKernelGGL(chunk_sort, dim3(NBUCK), dim3(256), 0, stream,
                       bucketed, chunkCursor, chunkOff, start, count, sorted_src);
    hipLaunchKernelGGL(gather_sum, dim3(25000), dim3(256), 0, stream,
                       xb, sorted_src, start, count, eps, accb);
    hipLaunchKernelGGL((gemm128<256, 512, true>), dim3(782 * 4), dim3(256), 0, stream,
                       accb, W1t, b1, (void*)tbuf, N_NODES);
    hipLaunchKernelGGL((gemm128<512, 256, false>), dim3(782 * 2), dim3(256), 0, stream,
                       tbuf, W2t, b2, (void*)h2, N_NODES);
    hipLaunchKernelGGL(col_stats1, dim3(500), dim3(256), 0, stream, h2, partial);
    hipLaunchKernelGGL(col_stats2, dim3(1), dim3(256), 0, stream, partial, gamma, beta, sc);
    hipLaunchKernelGGL(bn_apply, dim3(25000), dim3(256), 0, stream, h2, sc, out);
}

// Round 2
// 645.810 us; speedup vs baseline: 1.1853x; 1.0283x over previous
//
#include <hip/hip_runtime.h>
#include <hip/hip_bf16.h>
#include <stdint.h>

#define N_NODES 100000
#define DIM 256
#define HID 512
#define N_EDGES 1600000

// two-level bucket sort params: 782 buckets of 128 dst nodes each
#define NBUCK 782                  // 782*128 = 100096 >= N_NODES
#define BSHIFT 7
#define BMASK 127
#define CAPC 4096                  // per-bucket capacity (mean 2048)
#define CURSTRIDE 16               // one cursor per 64B line

using short8 = __attribute__((ext_vector_type(8))) short;
using f32x4  = __attribute__((ext_vector_type(4))) float;

__device__ __forceinline__ unsigned short f2bf(float f) {
    union { float f; unsigned u; } v; v.f = f;
    unsigned u = v.u;
    unsigned r = u + 0x7fffu + ((u >> 16) & 1u);   // RNE
    return (unsigned short)(r >> 16);
}
__device__ __forceinline__ float bf2f(unsigned short u) {
    union { unsigned u; float f; } v; v.u = ((unsigned)u) << 16; return v.f;
}
__device__ __forceinline__ void gload_lds16(const void* g, void* l) {
    __builtin_amdgcn_global_load_lds((const __attribute__((address_space(1))) void*)g,
                                     (__attribute__((address_space(3))) void*)l, 16, 0, 0);
}

// x fp32 -> bf16, 8 elems/thread
__global__ void x2bf(const float* __restrict__ x, unsigned short* __restrict__ xb) {
    long i = (long)blockIdx.x * blockDim.x + threadIdx.x;
    float4 u0 = ((const float4*)x)[i * 2];
    float4 u1 = ((const float4*)x)[i * 2 + 1];
    short8 o;
    o[0] = (short)f2bf(u0.x); o[1] = (short)f2bf(u0.y);
    o[2] = (short)f2bf(u0.z); o[3] = (short)f2bf(u0.w);
    o[4] = (short)f2bf(u1.x); o[5] = (short)f2bf(u1.y);
    o[6] = (short)f2bf(u1.z); o[7] = (short)f2bf(u1.w);
    ((short8*)xb)[i] = o;
}

// ---------------- two-level bucket sort (CSR by dst) ----------------

__global__ void zero_scratch(int* __restrict__ chunkCursor, float* __restrict__ gsums) {
    int i = blockIdx.x * 256 + threadIdx.x;
    if (i < NBUCK * CURSTRIDE) chunkCursor[i] = 0;
    if (i < 4096) gsums[i] = 0.0f;
}

// pass 1: scatter edges into fixed-stride buckets of 128 dst nodes.
// packed word: src (17 bits) | (dst & 127) << 17
__global__ void bucket_scatter(const int* __restrict__ src, const int* __restrict__ dst,
                               int* __restrict__ chunkCursor, int* __restrict__ bucketed) {
    int e = blockIdx.x * 256 + threadIdx.x;
    int d = dst[e];
    int c = d >> BSHIFT;
    int pos = atomicAdd(&chunkCursor[c * CURSTRIDE], 1);
    bucketed[(size_t)c * CAPC + pos] = src[e] | ((d & BMASK) << 17);
}

// exclusive scan of bucket counts (cursors after pass 1 ARE the counts)
__global__ void scan_chunks(const int* __restrict__ chunkCursor, int* __restrict__ chunkOff) {
    __shared__ int sm[1024];
    int t = threadIdx.x;
    int v = (t < NBUCK) ? chunkCursor[t * CURSTRIDE] : 0;
    sm[t] = v;
    __syncthreads();
    for (int off = 1; off < 1024; off <<= 1) {
        int add = (t >= off) ? sm[t - off] : 0;
        __syncthreads();
        sm[t] += add;
        __syncthreads();
    }
    chunkOff[t] = sm[t] - v;   // exclusive
}

// pass 2: per-bucket counting sort in LDS; per-node lists sorted by src
// (ascending) so concurrent gather waves sweep src-space together.
__global__ __launch_bounds__(256) void chunk_sort(const int* __restrict__ bucketed,
        const int* __restrict__ chunkCursor, const int* __restrict__ chunkOff,
        int* __restrict__ start, int* __restrict__ count, int* __restrict__ sorted_src) {
    __shared__ int cnt[128];
    __shared__ int cur[128];
    __shared__ int sortedL[CAPC];
    int c = blockIdx.x;
    int t = threadIdx.x;
    int nE = chunkCursor[c * CURSTRIDE];
    int base = chunkOff[c];
    const int* bk = bucketed + (size_t)c * CAPC;
    if (t < 128) cnt[t] = 0;
    __syncthreads();
    for (int i = t; i < nE; i += 256)
        atomicAdd(&cnt[bk[i] >> 17], 1);
    __syncthreads();
    int v = (t < 128) ? cnt[t] : 0;
    // Hillis-Steele inclusive scan over 128 bins
    for (int off = 1; off < 128; off <<= 1) {
        int add = (t >= off && t < 128) ? cnt[t - off] : 0;
        __syncthreads();
        if (t < 128) cnt[t] += add;
        __syncthreads();
    }
    int segs = 0, segc = 0;
    if (t < 128) {
        segc = v;
        segs = cnt[t] - v;
        int gid = c * 128 + t;
        start[gid] = base + segs;
        count[gid] = v;
        cur[t] = segs;
    }
    __syncthreads();
    for (int i = t; i < nE; i += 256) {
        int p = bk[i];
        int pos = atomicAdd(&cur[p >> 17], 1);
        sortedL[pos] = p & 0x1FFFF;
    }
    __syncthreads();
    // per-node insertion sort by src (avg 16 elems, max ~45)
    if (t < 128 && segc > 1) {
        for (int i = segs + 1; i < segs + segc; ++i) {
            int key = sortedL[i];
            int k = i - 1;
            while (k >= segs && sortedL[k] > key) { sortedL[k + 1] = sortedL[k]; --k; }
            sortedL[k + 1] = key;
        }
    }
    __syncthreads();
    for (int i = t; i < nE; i += 256)
        sorted_src[base + i] = sortedL[i];
}

// persistent grid-stride gather: one wave per node per round; 8-deep unrolled
// row loads. accb[n] = bf16( (1+eps)*x[n] + sum_neigh x[s] )
__global__ __launch_bounds__(256) void gather_sum(const unsigned short* __restrict__ xb,
        const int* __restrict__ sorted_src, const int* __restrict__ start,
        const int* __restrict__ count, const float* __restrict__ eps,
        unsigned short* __restrict__ accb) {
    int lane = threadIdx.x & 63;
    int wv = (blockIdx.x << 2) + (threadIdx.x >> 6);
    float s = 1.0f + eps[0];
    for (int n = wv; n < N_NODES; n += 8192) {
        ushort4 v = ((const ushort4*)(xb + (size_t)n * DIM))[lane];
        float a0 = bf2f(v.x) * s, a1 = bf2f(v.y) * s, a2 = bf2f(v.z) * s, a3 = bf2f(v.w) * s;
        int base = start[n];
        int end = base + count[n];
        int j = base;
        for (; j + 8 <= end; j += 8) {
            int i0 = sorted_src[j],     i1 = sorted_src[j + 1];
            int i2 = sorted_src[j + 2], i3 = sorted_src[j + 3];
            int i4 = sorted_src[j + 4], i5 = sorted_src[j + 5];
            int i6 = sorted_src[j + 6], i7 = sorted_src[j + 7];
            ushort4 v0 = ((const ushort4*)(xb + (size_t)i0 * DIM))[lane];
            ushort4 v1 = ((const ushort4*)(xb + (size_t)i1 * DIM))[lane];
            ushort4 v2 = ((const ushort4*)(xb + (size_t)i2 * DIM))[lane];
            ushort4 v3 = ((const ushort4*)(xb + (size_t)i3 * DIM))[lane];
            ushort4 v4 = ((const ushort4*)(xb + (size_t)i4 * DIM))[lane];
            ushort4 v5 = ((const ushort4*)(xb + (size_t)i5 * DIM))[lane];
            ushort4 v6 = ((const ushort4*)(xb + (size_t)i6 * DIM))[lane];
            ushort4 v7 = ((const ushort4*)(xb + (size_t)i7 * DIM))[lane];
            a0 += (bf2f(v0.x) + bf2f(v1.x)) + (bf2f(v2.x) + bf2f(v3.x))
                + (bf2f(v4.x) + bf2f(v5.x)) + (bf2f(v6.x) + bf2f(v7.x));
            a1 += (bf2f(v0.y) + bf2f(v1.y)) + (bf2f(v2.y) + bf2f(v3.y))
                + (bf2f(v4.y) + bf2f(v5.y)) + (bf2f(v6.y) + bf2f(v7.y));
            a2 += (bf2f(v0.z) + bf2f(v1.z)) + (bf2f(v2.z) + bf2f(v3.z))
                + (bf2f(v4.z) + bf2f(v5.z)) + (bf2f(v6.z) + bf2f(v7.z));
            a3 += (bf2f(v0.w) + bf2f(v1.w)) + (bf2f(v2.w) + bf2f(v3.w))
                + (bf2f(v4.w) + bf2f(v5.w)) + (bf2f(v6.w) + bf2f(v7.w));
        }
        for (; j + 2 <= end; j += 2) {
            int i0 = sorted_src[j], i1 = sorted_src[j + 1];
            ushort4 v0 = ((const ushort4*)(xb + (size_t)i0 * DIM))[lane];
            ushort4 v1 = ((const ushort4*)(xb + (size_t)i1 * DIM))[lane];
            a0 += bf2f(v0.x) + bf2f(v1.x);
            a1 += bf2f(v0.y) + bf2f(v1.y);
            a2 += bf2f(v0.z) + bf2f(v1.z);
            a3 += bf2f(v0.w) + bf2f(v1.w);
        }
        if (j < end) {
            int i0 = sorted_src[j];
            ushort4 v0 = ((const ushort4*)(xb + (size_t)i0 * DIM))[lane];
            a0 += bf2f(v0.x); a1 += bf2f(v0.y); a2 += bf2f(v0.z); a3 += bf2f(v0.w);
        }
        ushort4 o;
        o.x = f2bf(a0); o.y = f2bf(a1); o.z = f2bf(a2); o.w = f2bf(a3);
        ((ushort4*)(accb + (size_t)n * DIM))[lane] = o;
    }
}

// ---------------- MLP ----------------

__global__ void prep_weights(const float* __restrict__ W1, const float* __restrict__ W2,
                             unsigned short* __restrict__ W1t, unsigned short* __restrict__ W2t) {
    int tid = blockIdx.x * blockDim.x + threadIdx.x;
    if (tid < DIM * HID) {
        int n = tid >> 8, k = tid & 255;
        W1t[tid] = f2bf(W1[k * HID + n]);
    } else {
        int j = tid - DIM * HID;
        int n = j >> 9, k = j & 511;
        W2t[j] = f2bf(W2[k * DIM + n]);
    }
}

// 128x128 tile, 4 waves (2x2), each 64x64 via 4x4 of 16x16x32 bf16 MFMA.
// global_load_lds(16B) staging; LDS chunk XOR-swizzle keeps ds_read_b128 at 2-way.
// A row-major bf16 [M][K]; Bt n-major bf16 [NOUT][K].
// COLSTATS: fuse per-column sum / sum-of-squares into the epilogue (for BN).
template<int K, int NOUT, bool RELU_BF16_OUT, bool COLSTATS>
__global__ __launch_bounds__(256) void gemm128(const unsigned short* __restrict__ A,
        const unsigned short* __restrict__ Bt, const float* __restrict__ bias,
        void* __restrict__ Cout, float* __restrict__ gsums, int M) {
    __shared__ unsigned short As[128 * 32];   // 8 KB, row stride 64 B, no pad
    __shared__ unsigned short Bs[128 * 32];
    constexpr int NT = NOUT / 128;
    int mtile = blockIdx.x / NT;
    int ntile = blockIdx.x % NT;
    int mbase = mtile * 128, nbase = ntile * 128;
    int t = threadIdx.x;
    int lane = t & 63, wid = t >> 6;
    int wm = (wid & 1) * 64, wn = (wid >> 1) * 64;
    int lo = lane & 15, quad = lane >> 4;

    // staging slot -> (row, stored-chunk, global-chunk)
    int s0 = t, s1 = t + 256;
    int r0 = s0 >> 2, c0 = (s0 & 3) ^ ((r0 >> 1) & 3);
    int r1 = s1 >> 2, c1 = (s1 & 3) ^ ((r1 >> 1) & 3);
    int gmA0 = mbase + r0; if (gmA0 >= M) gmA0 = M - 1;
    int gmA1 = mbase + r1; if (gmA1 >= M) gmA1 = M - 1;
    const unsigned short* gA0 = A + (size_t)gmA0 * K + c0 * 8;
    const unsigned short* gA1 = A + (size_t)gmA1 * K + c1 * 8;
    const unsigned short* gB0 = Bt + (size_t)(nbase + r0) * K + c0 * 8;
    const unsigned short* gB1 = Bt + (size_t)(nbase + r1) * K + c1 * 8;
    char* lA0 = (char*)As + wid * 1024;
    char* lA1 = (char*)As + 4096 + wid * 1024;
    char* lB0 = (char*)Bs + wid * 1024;
    char* lB1 = (char*)Bs + 4096 + wid * 1024;

    // fragment LDS byte offsets (XOR-swizzled chunk)
    int offA[4], offB[4];
    #pragma unroll
    for (int i = 0; i < 4; ++i) {
        int ra = wm + i * 16 + lo;
        offA[i] = ra * 64 + ((quad ^ ((ra >> 1) & 3)) * 16);
        int rb = wn + i * 16 + lo;
        offB[i] = rb * 64 + ((quad ^ ((rb >> 1) & 3)) * 16);
    }

    f32x4 acc[4][4] = {};
    for (int kt = 0; kt < K / 32; ++kt) {
        if (kt) __syncthreads();
        int ko = kt * 32;
        gload_lds16(gA0 + ko, lA0);
        gload_lds16(gA1 + ko, lA1);
        gload_lds16(gB0 + ko, lB0);
        gload_lds16(gB1 + ko, lB1);
        __syncthreads();
        short8 a[4], b[4];
        #pragma unroll
        for (int i = 0; i < 4; ++i) {
            a[i] = *(const short8*)((const char*)As + offA[i]);
            b[i] = *(const short8*)((const char*)Bs + offB[i]);
        }
        #pragma unroll
        for (int mi = 0; mi < 4; ++mi)
            #pragma unroll
            for (int ni = 0; ni < 4; ++ni)
                acc[mi][ni] = __builtin_amdgcn_mfma_f32_16x16x32_bf16(a[mi], b[ni], acc[mi][ni], 0, 0, 0);
    }
    // epilogue: D layout col=lane&15, row=quad*4+reg
    float cs[4] = {0.f, 0.f, 0.f, 0.f}, cq[4] = {0.f, 0.f, 0.f, 0.f};
    #pragma unroll
    for (int mi = 0; mi < 4; ++mi)
      #pragma unroll
      for (int ni = 0; ni < 4; ++ni)
        #pragma unroll
        for (int r = 0; r < 4; ++r) {
            int row = mbase + wm + mi * 16 + quad * 4 + r;
            int col = nbase + wn + ni * 16 + lo;
            if (row < M) {
                float v = acc[mi][ni][r] + bias[col];
                if constexpr (RELU_BF16_OUT) {
                    v = fmaxf(v, 0.0f);
                    ((unsigned short*)Cout)[(size_t)row * NOUT + col] = f2bf(v);
                } else {
                    ((float*)Cout)[(size_t)row * NOUT + col] = v;
                }
                if constexpr (COLSTATS) { cs[ni] += v; cq[ni] += v * v; }
            }
        }
    if constexpr (COLSTATS) {
        __shared__ float colS[128], colQ[128];
        if (t < 128) { colS[t] = 0.f; colQ[t] = 0.f; }
        __syncthreads();
        #pragma unroll
        for (int ni = 0; ni < 4; ++ni) {
            float sv = cs[ni], qv = cq[ni];
            sv += __shfl_xor(sv, 16); sv += __shfl_xor(sv, 32);
            qv += __shfl_xor(qv, 16); qv += __shfl_xor(qv, 32);
            if (quad == 0) {
                atomicAdd(&colS[wn + ni * 16 + lo], sv);
                atomicAdd(&colQ[wn + ni * 16 + lo], qv);
            }
        }
        __syncthreads();
        if (t < 128) {
            int rep = blockIdx.x & 7;
            atomicAdd(&gsums[rep * 512 + nbase + t], colS[t]);
            atomicAdd(&gsums[rep * 512 + 256 + nbase + t], colQ[t]);
        }
    }
}

// ---------------- BatchNorm ----------------

__global__ void col_stats2(const float* __restrict__ gsums, const float* __restrict__ gamma,
                           const float* __restrict__ beta, float* __restrict__ sc) {
    int t = threadIdx.x;
    float s = 0.f, q = 0.f;
    for (int rep = 0; rep < 8; ++rep) {
        s += gsums[rep * 512 + t];
        q += gsums[rep * 512 + 256 + t];
    }
    float mean = s * (1.0f / (float)N_NODES);
    float var = q * (1.0f / (float)N_NODES) - mean * mean;
    float inv = rsqrtf(var + 1e-5f);
    float scale = gamma[t] * inv;
    sc[t] = scale;
    sc[256 + t] = beta[t] - mean * scale;
}

__global__ void bn_apply(const float* __restrict__ h, const float* __restrict__ sc,
                         float* __restrict__ out) {
    long i = (long)blockIdx.x * blockDim.x + threadIdx.x;
    int c = (int)((i * 4) & (DIM - 1));
    float4 v = ((const float4*)h)[i];
    float4 scale = *(const float4*)(sc + c);
    float4 shift = *(const float4*)(sc + 256 + c);
    float4 o;
    o.x = v.x * scale.x + shift.x;
    o.y = v.y * scale.y + shift.y;
    o.z = v.z * scale.z + shift.z;
    o.w = v.w * scale.w + shift.w;
    ((float4*)out)[i] = o;
}

extern "C" void kernel_launch(void* const* d_in, const int* in_sizes, int n_in,
                              void* d_out, int out_size, void* d_ws, size_t ws_size,
                              hipStream_t stream) {
    const float* x     = (const float*)d_in[0];
    const int*   src   = (const int*)d_in[1];
    const int*   dst   = (const int*)d_in[2];
    const float* eps   = (const float*)d_in[3];
    const float* W1    = (const float*)d_in[4];
    const float* b1    = (const float*)d_in[5];
    const float* W2    = (const float*)d_in[6];
    const float* b2    = (const float*)d_in[7];
    const float* gamma = (const float*)d_in[8];
    const float* beta  = (const float*)d_in[9];

    char* ws = (char*)d_ws;
    unsigned short* xb   = (unsigned short*)ws;                   // 51,200,000 B (dead after gather)
    unsigned short* accb = (unsigned short*)(ws + 51200000);      // 51,200,000 B (dead after GEMM1)
    float*          h2   = (float*)ws;                            // 102,400,000 B (overlaps xb+accb, written by GEMM2)
    unsigned short* W1t  = (unsigned short*)(ws + 102400000);     // 262,144 B
    unsigned short* W2t  = (unsigned short*)(ws + 102662144);     // 262,144 B
    float*          sc   = (float*)(ws + 102924288);              // 2,048 B
    float*          gsums = (float*)(ws + 102926336);             // 8 reps x 512 floats = 16,384 B

    // d_out phases: [sort scratch] -> [tbuf bf16 N x 512] -> [final out]
    char* ob = (char*)d_out;
    int* chunkCursor = (int*)ob;                   // 782*16*4 = 50,048 B (padded to 51,200)
    int* chunkOff    = (int*)(ob + 51200);         // 4,096 B
    int* start       = (int*)(ob + 55296);         // 400,384 B
    int* count       = (int*)(ob + 455680);        // 400,384 B
    int* sorted_src  = (int*)(ob + 856064);        // 6,400,000 B
    int* bucketed    = (int*)(ob + 7256064);       // 782*4096*4 = 12,812,288 B (ends at 20,068,352)
    unsigned short* tbuf = (unsigned short*)d_out;
    float*          out  = (float*)d_out;

    hipLaunchKernelGGL(x2bf, dim3(12500), dim3(256), 0, stream, x, xb);
    hipLaunchKernelGGL(prep_weights, dim3(1024), dim3(256), 0, stream, W1, W2, W1t, W2t);
    hipLaunchKernelGGL(zero_scratch, dim3(49), dim3(256), 0, stream, chunkCursor, gsums);
    hipLaunchKernelGGL(bucket_scatter, dim3(N_EDGES / 256), dim3(256), 0, stream,
                       src, dst, chunkCursor, bucketed);
    hipLaunchKernelGGL(scan_chunks, dim3(1), dim3(1024), 0, stream, chunkCursor, chunkOff);
    hipLaunchKernelGGL(chunk_sort, dim3(NBUCK), dim3(256), 0, stream,
                       bucketed, chunkCursor, chunkOff, start, count, sorted_src);
    hipLaunchKernelGGL(gather_sum, dim3(2048), dim3(256), 0, stream,
                       xb, sorted_src, start, count, eps, accb);
    hipLaunchKernelGGL((gemm128<256, 512, true, false>), dim3(782 * 4), dim3(256), 0, stream,
                       accb, W1t, b1, (void*)tbuf, nullptr, N_NODES);
    hipLaunchKernelGGL((gemm128<512, 256, false, true>), dim3(782 * 2), dim3(256), 0, stream,
                       tbuf, W2t, b2, (void*)h2, gsums, N_NODES);
    hipLaunchKernelGGL(col_stats2, dim3(1), dim3(256), 0, stream, gsums, gamma, beta, sc);
    hipLaunchKernelGGL(bn_apply, dim3(25000), dim3(256), 0, stream, h2, sc, out);
}

// Round 5
// 573.140 us; speedup vs baseline: 1.3356x; 1.1268x over previous
//
#include <hip/hip_runtime.h>
#include <hip/hip_bf16.h>
#include <stdint.h>

#define N_NODES 100000
#define DIM 256
#define HID 512
#define N_EDGES 1600000

#define NBUCK 782
#define BSHIFT 7
#define BMASK 127
#define CAPC 4096
#define CURSTRIDE 16

using short8 = __attribute__((ext_vector_type(8))) short;
using f32x4  = __attribute__((ext_vector_type(4))) float;

__device__ __forceinline__ unsigned short f2bf(float f) {
    union { float f; unsigned u; } v; v.f = f;
    unsigned u = v.u;
    unsigned r = u + 0x7fffu + ((u >> 16) & 1u);
    return (unsigned short)(r >> 16);
}
__device__ __forceinline__ float bf2f(unsigned short u) {
    union { unsigned u; float f; } v; v.u = ((unsigned)u) << 16; return v.f;
}
__device__ __forceinline__ void gload_lds16(const void* g, void* l) {
    __builtin_amdgcn_global_load_lds((const __attribute__((address_space(1))) void*)g,
                                     (__attribute__((address_space(3))) void*)l, 16, 0, 0);
}

// merged prologue: x2bf (blocks 0..12499) || prep_weights (12500..13523) || zero (13524..)
__global__ void prep_all(const float* __restrict__ x, unsigned short* __restrict__ xb,
                         const float* __restrict__ W1, const float* __restrict__ W2,
                         unsigned short* __restrict__ W1t, unsigned short* __restrict__ W2t,
                         int* __restrict__ chunkCursor, float* __restrict__ gsums) {
    int b = blockIdx.x;
    int t = threadIdx.x;
    if (b < 12500) {
        long i = (long)b * 256 + t;
        float4 u0 = ((const float4*)x)[i * 2];
        float4 u1 = ((const float4*)x)[i * 2 + 1];
        short8 o;
        o[0] = (short)f2bf(u0.x); o[1] = (short)f2bf(u0.y);
        o[2] = (short)f2bf(u0.z); o[3] = (short)f2bf(u0.w);
        o[4] = (short)f2bf(u1.x); o[5] = (short)f2bf(u1.y);
        o[6] = (short)f2bf(u1.z); o[7] = (short)f2bf(u1.w);
        ((short8*)xb)[i] = o;
    } else if (b < 13524) {
        int tid = (b - 12500) * 256 + t;
        if (tid < DIM * HID) {
            int n = tid >> 8, k = tid & 255;
            W1t[tid] = f2bf(W1[k * HID + n]);
        } else {
            int j = tid - DIM * HID;
            int n = j >> 9, k = j & 511;
            W2t[j] = f2bf(W2[k * DIM + n]);
        }
    } else {
        int i = (b - 13524) * 256 + t;
        if (i < NBUCK * CURSTRIDE) chunkCursor[i] = 0;
        if (i < 4096) gsums[i] = 0.0f;
    }
}

// pass 1: scatter edges into fixed-stride buckets of 128 dst nodes.
// packed word: src (17 bits) | (dst & 127) << 17
__global__ void bucket_scatter(const int* __restrict__ src, const int* __restrict__ dst,
                               int* __restrict__ chunkCursor, int* __restrict__ bucketed) {
    int e = blockIdx.x * 256 + threadIdx.x;
    int d = dst[e];
    int c = d >> BSHIFT;
    int pos = atomicAdd(&chunkCursor[c * CURSTRIDE], 1);
    bucketed[(size_t)c * CAPC + pos] = src[e] | ((d & BMASK) << 17);
}

// pass 2: per-bucket counting sort in LDS, written back IN PLACE.
// start[] points into the fixed-stride bucket region (CSR need not be
// contiguous: the only consumer is gather_sum via start/count).
__global__ __launch_bounds__(256) void chunk_sort(int* __restrict__ bucketed,
        const int* __restrict__ chunkCursor,
        int* __restrict__ start, int* __restrict__ count) {
    __shared__ int cnt[128];
    __shared__ int cur[128];
    __shared__ int sortedL[CAPC];
    int c = blockIdx.x;
    int t = threadIdx.x;
    int nE = chunkCursor[c * CURSTRIDE];
    int* bk = bucketed + (size_t)c * CAPC;
    if (t < 128) cnt[t] = 0;
    __syncthreads();
    for (int i = t; i < nE; i += 256)
        atomicAdd(&cnt[bk[i] >> 17], 1);
    __syncthreads();
    int v = (t < 128) ? cnt[t] : 0;
    for (int off = 1; off < 128; off <<= 1) {
        int add = (t >= off && t < 128) ? cnt[t - off] : 0;
        __syncthreads();
        if (t < 128) cnt[t] += add;
        __syncthreads();
    }
    if (t < 128) {
        int excl = cnt[t] - v;
        int gid = c * 128 + t;
        start[gid] = c * CAPC + excl;
        count[gid] = v;
        cur[t] = excl;
    }
    __syncthreads();
    for (int i = t; i < nE; i += 256) {
        int p = bk[i];
        int pos = atomicAdd(&cur[p >> 17], 1);
        sortedL[pos] = p & 0x1FFFF;
    }
    __syncthreads();
    for (int i = t; i < nE; i += 256)
        bk[i] = sortedL[i];
}

// one wave per node: accb[n] = bf16( (1+eps)*x[n] + sum_neigh x[s] )
__global__ void gather_sum(const unsigned short* __restrict__ xb, const int* __restrict__ sorted_src,
                           const int* __restrict__ start, const int* __restrict__ count,
                           const float* __restrict__ eps, unsigned short* __restrict__ accb) {
    int lane = threadIdx.x & 63;
    int n = blockIdx.x * 4 + (threadIdx.x >> 6);
    if (n >= N_NODES) return;
    float s = 1.0f + eps[0];
    const ushort4* xr = (const ushort4*)(xb + (size_t)n * DIM);
    ushort4 v = xr[lane];
    float a0 = bf2f(v.x) * s, a1 = bf2f(v.y) * s, a2 = bf2f(v.z) * s, a3 = bf2f(v.w) * s;
    int base = start[n];
    int end = base + count[n];
    int j = base;
    for (; j + 4 <= end; j += 4) {
        int s0 = sorted_src[j], s1 = sorted_src[j + 1];
        int s2 = sorted_src[j + 2], s3 = sorted_src[j + 3];
        ushort4 v0 = ((const ushort4*)(xb + (size_t)s0 * DIM))[lane];
        ushort4 v1 = ((const ushort4*)(xb + (size_t)s1 * DIM))[lane];
        ushort4 v2 = ((const ushort4*)(xb + (size_t)s2 * DIM))[lane];
        ushort4 v3 = ((const ushort4*)(xb + (size_t)s3 * DIM))[lane];
        a0 += bf2f(v0.x) + bf2f(v1.x) + bf2f(v2.x) + bf2f(v3.x);
        a1 += bf2f(v0.y) + bf2f(v1.y) + bf2f(v2.y) + bf2f(v3.y);
        a2 += bf2f(v0.z) + bf2f(v1.z) + bf2f(v2.z) + bf2f(v3.z);
        a3 += bf2f(v0.w) + bf2f(v1.w) + bf2f(v2.w) + bf2f(v3.w);
    }
    for (; j < end; ++j) {
        int s0 = sorted_src[j];
        ushort4 v0 = ((const ushort4*)(xb + (size_t)s0 * DIM))[lane];
        a0 += bf2f(v0.x); a1 += bf2f(v0.y); a2 += bf2f(v0.z); a3 += bf2f(v0.w);
    }
    ushort4 o;
    o.x = f2bf(a0); o.y = f2bf(a1); o.z = f2bf(a2); o.w = f2bf(a3);
    ((ushort4*)(accb + (size_t)n * DIM))[lane] = o;
}

// ---------------- MLP ----------------

// 128x128 tile, 4 waves (2x2), each 64x64 via 4x4 of 16x16x32 bf16 MFMA.
// XCD-aware swizzle: all NT ntiles of one mtile land on the SAME XCD
// (positions p, p+8 round-robin to the same XCD) so the A-panel is fetched
// into that XCD's L2 once instead of NT times.
// COLSTATS: fuse per-column sum / sum-of-squares into the epilogue (for BN).
template<int K, int NOUT, bool RELU_BF16_OUT, bool COLSTATS>
__global__ __launch_bounds__(256) void gemm128(const unsigned short* __restrict__ A,
        const unsigned short* __restrict__ Bt, const float* __restrict__ bias,
        void* __restrict__ Cout, float* __restrict__ gsums, int M) {
    __shared__ unsigned short As[128 * 32];
    __shared__ unsigned short Bs[128 * 32];
    constexpr int NT = NOUT / 128;
    constexpr int NTLOG = (NT == 4) ? 2 : 1;
    int L = blockIdx.x;
    int x8 = L & 7;
    int ntile = (L >> 3) & (NT - 1);
    int mtile = (L >> (3 + NTLOG)) * 8 + x8;
    int MT = (M + 127) >> 7;
    if (mtile >= MT) return;
    int mbase = mtile * 128, nbase = ntile * 128;
    int t = threadIdx.x;
    int lane = t & 63, wid = t >> 6;
    int wm = (wid & 1) * 64, wn = (wid >> 1) * 64;
    int lo = lane & 15, quad = lane >> 4;

    int s0 = t, s1 = t + 256;
    int r0 = s0 >> 2, c0 = (s0 & 3) ^ ((r0 >> 1) & 3);
    int r1 = s1 >> 2, c1 = (s1 & 3) ^ ((r1 >> 1) & 3);
    int gmA0 = mbase + r0; if (gmA0 >= M) gmA0 = M - 1;
    int gmA1 = mbase + r1; if (gmA1 >= M) gmA1 = M - 1;
    const unsigned short* gA0 = A + (size_t)gmA0 * K + c0 * 8;
    const unsigned short* gA1 = A + (size_t)gmA1 * K + c1 * 8;
    const unsigned short* gB0 = Bt + (size_t)(nbase + r0) * K + c0 * 8;
    const unsigned short* gB1 = Bt + (size_t)(nbase + r1) * K + c1 * 8;
    char* lA0 = (char*)As + wid * 1024;
    char* lA1 = (char*)As + 4096 + wid * 1024;
    char* lB0 = (char*)Bs + wid * 1024;
    char* lB1 = (char*)Bs + 4096 + wid * 1024;

    int offA[4], offB[4];
    #pragma unroll
    for (int i = 0; i < 4; ++i) {
        int ra = wm + i * 16 + lo;
        offA[i] = ra * 64 + ((quad ^ ((ra >> 1) & 3)) * 16);
        int rb = wn + i * 16 + lo;
        offB[i] = rb * 64 + ((quad ^ ((rb >> 1) & 3)) * 16);
    }

    f32x4 acc[4][4] = {};
    for (int kt = 0; kt < K / 32; ++kt) {
        if (kt) __syncthreads();
        int ko = kt * 32;
        gload_lds16(gA0 + ko, lA0);
        gload_lds16(gA1 + ko, lA1);
        gload_lds16(gB0 + ko, lB0);
        gload_lds16(gB1 + ko, lB1);
        __syncthreads();
        short8 a[4], b[4];
        #pragma unroll
        for (int i = 0; i < 4; ++i) {
            a[i] = *(const short8*)((const char*)As + offA[i]);
            b[i] = *(const short8*)((const char*)Bs + offB[i]);
        }
        #pragma unroll
        for (int mi = 0; mi < 4; ++mi)
            #pragma unroll
            for (int ni = 0; ni < 4; ++ni)
                acc[mi][ni] = __builtin_amdgcn_mfma_f32_16x16x32_bf16(a[mi], b[ni], acc[mi][ni], 0, 0, 0);
    }
    float cs[4] = {0.f, 0.f, 0.f, 0.f}, cq[4] = {0.f, 0.f, 0.f, 0.f};
    #pragma unroll
    for (int mi = 0; mi < 4; ++mi)
      #pragma unroll
      for (int ni = 0; ni < 4; ++ni)
        #pragma unroll
        for (int r = 0; r < 4; ++r) {
            int row = mbase + wm + mi * 16 + quad * 4 + r;
            int col = nbase + wn + ni * 16 + lo;
            if (row < M) {
                float v = acc[mi][ni][r] + bias[col];
                if constexpr (RELU_BF16_OUT) {
                    v = fmaxf(v, 0.0f);
                    ((unsigned short*)Cout)[(size_t)row * NOUT + col] = f2bf(v);
                } else {
                    ((float*)Cout)[(size_t)row * NOUT + col] = v;
                }
                if constexpr (COLSTATS) { cs[ni] += v; cq[ni] += v * v; }
            }
        }
    if constexpr (COLSTATS) {
        __shared__ float colS[128], colQ[128];
        if (t < 128) { colS[t] = 0.f; colQ[t] = 0.f; }
        __syncthreads();
        #pragma unroll
        for (int ni = 0; ni < 4; ++ni) {
            float sv = cs[ni], qv = cq[ni];
            sv += __shfl_xor(sv, 16); sv += __shfl_xor(sv, 32);
            qv += __shfl_xor(qv, 16); qv += __shfl_xor(qv, 32);
            if (quad == 0) {
                atomicAdd(&colS[wn + ni * 16 + lo], sv);
                atomicAdd(&colQ[wn + ni * 16 + lo], qv);
            }
        }
        __syncthreads();
        if (t < 128) {
            int rep = x8;
            atomicAdd(&gsums[rep * 512 + nbase + t], colS[t]);
            atomicAdd(&gsums[rep * 512 + 256 + nbase + t], colQ[t]);
        }
    }
}

// ---------------- BatchNorm ----------------

__global__ void col_stats2(const float* __restrict__ gsums, const float* __restrict__ gamma,
                           const float* __restrict__ beta, float* __restrict__ sc) {
    int t = threadIdx.x;
    float s = 0.f, q = 0.f;
    for (int rep = 0; rep < 8; ++rep) {
        s += gsums[rep * 512 + t];
        q += gsums[rep * 512 + 256 + t];
    }
    float mean = s * (1.0f / (float)N_NODES);
    float var = q * (1.0f / (float)N_NODES) - mean * mean;
    float inv = rsqrtf(var + 1e-5f);
    float scale = gamma[t] * inv;
    sc[t] = scale;
    sc[256 + t] = beta[t] - mean * scale;
}

__global__ void bn_apply(const float* __restrict__ h, const float* __restrict__ sc,
                         float* __restrict__ out) {
    long i = (long)blockIdx.x * blockDim.x + threadIdx.x;
    int c = (int)((i * 4) & (DIM - 1));
    float4 v = ((const float4*)h)[i];
    float4 scale = *(const float4*)(sc + c);
    float4 shift = *(const float4*)(sc + 256 + c);
    float4 o;
    o.x = v.x * scale.x + shift.x;
    o.y = v.y * scale.y + shift.y;
    o.z = v.z * scale.z + shift.z;
    o.w = v.w * scale.w + shift.w;
    ((float4*)out)[i] = o;
}

extern "C" void kernel_launch(void* const* d_in, const int* in_sizes, int n_in,
                              void* d_out, int out_size, void* d_ws, size_t ws_size,
                              hipStream_t stream) {
    const float* x     = (const float*)d_in[0];
    const int*   src   = (const int*)d_in[1];
    const int*   dst   = (const int*)d_in[2];
    const float* eps   = (const float*)d_in[3];
    const float* W1    = (const float*)d_in[4];
    const float* b1    = (const float*)d_in[5];
    const float* W2    = (const float*)d_in[6];
    const float* b2    = (const float*)d_in[7];
    const float* gamma = (const float*)d_in[8];
    const float* beta  = (const float*)d_in[9];

    char* ws = (char*)d_ws;
    unsigned short* xb   = (unsigned short*)ws;                   // 51,200,000 B (dead after gather)
    unsigned short* accb = (unsigned short*)(ws + 51200000);      // 51,200,000 B (dead after GEMM1)
    float*          h2   = (float*)ws;                            // 102,400,000 B (overlaps xb+accb)
    unsigned short* W1t  = (unsigned short*)(ws + 102400000);     // 262,144 B
    unsigned short* W2t  = (unsigned short*)(ws + 102662144);     // 262,144 B
    float*          sc   = (float*)(ws + 102924288);              // 2,048 B
    float*          gsums = (float*)(ws + 102926336);             // 16,384 B

    char* ob = (char*)d_out;
    int* chunkCursor = (int*)ob;                   // 50,048 B (padded to 51,200)
    int* start       = (int*)(ob + 51200);         // 400,384 B
    int* count       = (int*)(ob + 451584);        // 400,384 B
    int* bucketed    = (int*)(ob + 851968);        // 12,812,288 B (ends at 13,664,256)
    unsigned short* tbuf = (unsigned short*)d_out;
    float*          out  = (float*)d_out;

    hipLaunchKernelGGL(prep_all, dim3(13573), dim3(256), 0, stream,
                       x, xb, W1, W2, W1t, W2t, chunkCursor, gsums);
    hipLaunchKernelGGL(bucket_scatter, dim3(N_EDGES / 256), dim3(256), 0, stream,
                       src, dst, chunkCursor, bucketed);
    hipLaunchKernelGGL(chunk_sort, dim3(NBUCK), dim3(256), 0, stream,
                       bucketed, chunkCursor, start, count);
    hipLaunchKernelGGL(gather_sum, dim3(25000), dim3(256), 0, stream,
                       xb, bucketed, start, count, eps, accb);
    hipLaunchKernelGGL((gemm128<256, 512, true, false>), dim3(784 * 4), dim3(256), 0, stream,
                       accb, W1t, b1, (void*)tbuf, nullptr, N_NODES);
    hipLaunchKernelGGL((gemm128<512, 256, false, true>), dim3(784 * 2), dim3(256), 0, stream,
                       tbuf, W2t, b2, (void*)h2, gsums, N_NODES);
    hipLaunchKernelGGL(col_stats2, dim3(1), dim3(256), 0, stream, gsums, gamma, beta, sc);
    hipLaunchKernelGGL(bn_apply, dim3(25000), dim3(256), 0, stream, h2, sc, out);
}